// Round 3
// baseline (1009.047 us; speedup 1.0000x reference)
//
#include <hip/hip_runtime.h>
#include <hip/hip_cooperative_groups.h>
#include <math.h>

namespace cg = cooperative_groups;

#define C  2048
#define L  4096
#define L2 2048
#define CW3 6144  // C*3

// ---- small arrays in d_ws (float offsets) ----
constexpr size_t OFF_RS_A = 0;      // 2048
constexpr size_t OFF_RQ_A = 2048;   // 2048
constexpr size_t OFF_RS_B = 4096;   // 2048
constexpr size_t OFF_RQ_B = 6144;   // 2048
constexpr size_t OFF_SCAL = 8192;   // 16: [0]=meanA [1]=coefA [2]=meanB [3]=coefB [4]=sum(fc_b)
constexpr size_t OFF_CW   = 8208;   // 2048 colsum(fc_w)
constexpr size_t OFF_S    = 10256;  // 2048
constexpr size_t OFF_V    = 12304;  // 2048 (atomic-accumulated, NO bias)
constexpr size_t OFF_O2   = 14352;  // 2048 (contiguous after V)
constexpr size_t OFF_MIX  = 16400;  // 2048
constexpr size_t OFF_OV   = 18448;  // 2048
constexpr size_t OFF_U    = 20496;  // 6144
constexpr size_t OFF_G    = 26640;  // 6144 (atomic; zeroed in S2)
constexpr size_t OFF_H    = 32784;  // 6144 (contiguous after G)

// ---- big scratch staged in d_out (fully overwritten by final stage) ----
constexpr size_t SC_CWP = 0;        // 32*2048
constexpr size_t SC_VP  = 65536;    // 256*2048 (fallback path only)
constexpr size_t SC_O2P = 589824;   // 256*2048 (fallback path only)

__device__ __forceinline__ float wredf(float v) {
#pragma unroll
  for (int o = 32; o; o >>= 1) v += __shfl_down(v, o, 64);
  return v;
}
__device__ __forceinline__ double wredd(double v) {
#pragma unroll
  for (int o = 32; o; o >>= 1) v += __shfl_down(v, o, 64);
  return v;
}
__device__ __forceinline__ float sigm(float x) { return 1.f / (1.f + expf(-x)); }
__device__ __forceinline__ float simam1(float x, float m, float cf) {
  float d = x - m;
  float y = d * d * cf + 0.5f;
  return x * (1.f + 1.f / (1.f + expf(-y)));
}

// ================= ONE cooperative mega-kernel: all 8 stages =================
__global__ __launch_bounds__(256, 4) void mega(
    const float* __restrict__ input, const float* __restrict__ insum,
    const float* __restrict__ conv1_w, const float* __restrict__ fc_w,
    const float* __restrict__ fc_b, const float* __restrict__ mix_w,
    float* __restrict__ out, float* __restrict__ ws) {
  cg::grid_group grid = cg::this_grid();
  float* sc = out;
  __shared__ float shf[12];
  __shared__ float shl[32], shs[32];
  __shared__ double shd[5];
  const int tid = threadIdx.x;
  const int lane = tid & 63, wv = tid >> 6;
  const int nb = gridDim.x;

  // ---- S1: rowstats(input,insum) + fc_w colsum partials ----
  for (int u = blockIdx.x; u < 4352; u += nb) {
    if (u < 4096) {
      const float* src = (u < 2048) ? input : insum;
      int row = u & 2047;
      const float4* p = (const float4*)(src + (size_t)row * L);
      float s = 0.f, q = 0.f;
#pragma unroll
      for (int i = tid; i < L / 4; i += 256) {
        float4 v = p[i];
        s += (v.x + v.y) + (v.z + v.w);
        q += (v.x * v.x + v.y * v.y) + (v.z * v.z + v.w * v.w);
      }
      s = wredf(s); q = wredf(q);
      if (!lane) { shf[wv] = s; shf[4 + wv] = q; }
      __syncthreads();
      if (!tid) {
        float* rs = ws + ((u < 2048) ? OFF_RS_A : OFF_RS_B);
        float* rq = ws + ((u < 2048) ? OFF_RQ_A : OFF_RQ_B);
        rs[row] = shf[0] + shf[1] + shf[2] + shf[3];
        rq[row] = shf[4] + shf[5] + shf[6] + shf[7];
      }
      __syncthreads();
    } else {
      int cb = u - 4096;
      int col = (cb & 7) * 256 + tid;
      int r0 = (cb >> 3) * 64;
      const float* p = fc_w + (size_t)r0 * C + col;
      float acc = 0.f;
#pragma unroll 8
      for (int k = 0; k < 64; ++k) acc += p[(size_t)k * C];
      (sc + SC_CWP)[(cb >> 3) * C + col] = acc;
    }
  }
  grid.sync();

  // ---- S2: s[2048] + cw final[8] + scalars[1] + zero G/H/V/O2[64] ----
  for (int u = blockIdx.x; u < 2121; u += nb) {
    if (u < 2048) {
      const float4* w = (const float4*)(fc_w + (size_t)u * C);
      const float4* rx = (const float4*)(ws + OFF_RS_A);
      float acc = 0.f;
#pragma unroll
      for (int i = tid; i < C / 4; i += 256) {
        float4 a = w[i], r = rx[i];
        acc += a.x * r.x + a.y * r.y + a.z * r.z + a.w * r.w;
      }
      acc = wredf(acc);
      if (!lane) shf[wv] = acc;
      __syncthreads();
      if (!tid)
        (ws + OFF_S)[u] = 0.5f * (shf[0] + shf[1] + shf[2] + shf[3]) + (float)L2 * fc_b[u];
      __syncthreads();
    } else if (u < 2056) {
      int i = (u - 2048) * 256 + tid;
      float acc = 0.f;
#pragma unroll
      for (int br = 0; br < 32; ++br) acc += (sc + SC_CWP)[br * C + i];
      (ws + OFF_CW)[i] = acc;
    } else if (u == 2056) {
      const float* arr = ws + (wv == 0 ? OFF_RS_A : wv == 1 ? OFF_RQ_A
                                                            : wv == 2 ? OFF_RS_B : OFF_RQ_B);
      double acc = 0.0, accb = 0.0;
      for (int i = lane; i < 2048; i += 64) {
        acc += (double)arr[i];
        if (wv == 0) accb += (double)fc_b[i];
      }
      acc = wredd(acc);
      if (wv == 0) accb = wredd(accb);
      if (!lane) { shd[wv] = acc; if (wv == 0) shd[4] = accb; }
      __syncthreads();
      if (!tid) {
        const double N = (double)C * (double)L, n = N - 1.0;
        double dA = shd[1] - shd[0] * shd[0] / N;
        double dB = shd[3] - shd[2] * shd[2] / N;
        float* s = ws + OFF_SCAL;
        s[0] = (float)(shd[0] / N);
        s[1] = (float)(1.0 / (4.0 * (dA / n + 1e-4)));
        s[2] = (float)(shd[2] / N);
        s[3] = (float)(1.0 / (4.0 * (dB / n + 1e-4)));
        s[4] = (float)shd[4];
      }
      __syncthreads();
    } else {
      int idx = (u - 2057) * 256 + tid;  // [0, 16384)
      if (idx < 12288) ws[OFF_G + idx] = 0.f;        // G,H contiguous
      else             ws[OFF_V + idx - 12288] = 0.f; // V,O2 contiguous
    }
  }
  grid.sync();

  // ---- S3: g/h from conv1_w via atomics ----
  for (int u = blockIdx.x; u < 1536; u += nb) {
    int col = (u % 24) * 256 + tid;   // [0, 6144)
    int i0 = (u / 24) * 32;
    if (tid < 32) {
      shl[tid] = (ws + OFF_CW)[i0 + tid];
      shs[tid] = (ws + OFF_S)[i0 + tid];
    }
    __syncthreads();
    const float* base = conv1_w + (size_t)i0 * CW3 + col;
    float ag = 0.f, ah = 0.f;
#pragma unroll 8
    for (int k = 0; k < 32; ++k) {
      float wvv = base[(size_t)k * CW3];
      ag += shl[k] * wvv;
      ah += shs[k] * wvv;
    }
    atomicAdd(ws + OFF_G + col, ag);
    atomicAdd(ws + OFF_H + col, ah);
    __syncthreads();
  }
  grid.sync();

  // ---- S4: v/o2 accumulated directly via atomics ----
  for (int u = blockIdx.x; u < 2048; u += nb) {
    int k = (u & 7) * 256 + tid;
    int c0 = (u >> 3) * 8;
    const float* g = ws + OFF_G;
    const float* h = ws + OFF_H;
    float accv = 0.f, acco = 0.f;
#pragma unroll
    for (int c = c0; c < c0 + 8; ++c) {
      const float* row = insum + (size_t)c * L;
      float2 bm = *(const float2*)(row + 2 * k);
      float xc = (bm.x + bm.y) * 0.5f;
      float xl = 0.f, xr = 0.f;
      if (k > 0) {
        float2 am = *(const float2*)(row + 2 * k - 2);
        xl = (am.x + am.y) * 0.5f;
      }
      if (k < L2 - 1) {
        float2 dm = *(const float2*)(row + 2 * k + 2);
        xr = (dm.x + dm.y) * 0.5f;
      }
      accv += g[c * 3] * xl + g[c * 3 + 1] * xc + g[c * 3 + 2] * xr;
      acco += h[c * 3] * xl + h[c * 3 + 1] * xc + h[c * 3 + 2] * xr;
    }
    atomicAdd(ws + OFF_V + k, accv);
    atomicAdd(ws + OFF_O2 + k, acco);
  }
  grid.sync();

  // ---- S5: U correlations (bias folded in) ----
  for (int u = blockIdx.x; u < 2048; u += nb) {
    const float* v = ws + OFF_V;
    float sb = (ws + OFF_SCAL)[4];
    float a0 = 0.f, a1 = 0.f, a2 = 0.f;
    for (int j = tid; j < L2; j += 256) {
      float2 ab = *(const float2*)(input + (size_t)u * L + 2 * j);
      float xmv = (ab.x + ab.y) * 0.5f;
      float vp = (j + 1 < L2) ? v[j + 1] + sb : 0.f;
      float vc = v[j] + sb;
      float vm = j ? v[j - 1] + sb : 0.f;
      a0 += xmv * vp;
      a1 += xmv * vc;
      a2 += xmv * vm;
    }
    a0 = wredf(a0); a1 = wredf(a1); a2 = wredf(a2);
    if (!lane) { shf[wv] = a0; shf[4 + wv] = a1; shf[8 + wv] = a2; }
    __syncthreads();
    if (!tid) {
      (ws + OFF_U)[u * 3 + 0] = shf[0] + shf[1] + shf[2] + shf[3];
      (ws + OFF_U)[u * 3 + 1] = shf[4] + shf[5] + shf[6] + shf[7];
      (ws + OFF_U)[u * 3 + 2] = shf[8] + shf[9] + shf[10] + shf[11];
    }
    __syncthreads();
  }
  grid.sync();

  // ---- S6: out1 + mix ----
  for (int u = blockIdx.x; u < 2048; u += nb) {
    const float4* w4 = (const float4*)(conv1_w + (size_t)u * CW3);
    const float4* u4 = (const float4*)(ws + OFF_U);
    float acc = 0.f;
#pragma unroll
    for (int m = tid; m < CW3 / 4; m += 256) {
      float4 wvv = w4[m], uv = u4[m];
      acc += wvv.x * uv.x + wvv.y * uv.y + wvv.z * uv.z + wvv.w * uv.w;
    }
    acc = wredf(acc);
    if (!lane) shf[wv] = acc;
    __syncthreads();
    if (!tid) {
      float mfv = sigm(mix_w[0]);
      float o1 = sigm(shf[0] + shf[1] + shf[2] + shf[3]);
      float o2 = sigm((ws + OFF_O2)[u]);
      (ws + OFF_MIX)[u] = o1 * mfv + o2 * (1.f - mfv);
    }
    __syncthreads();
  }
  grid.sync();

  // ---- S7: ov via mid-taps ----
  for (int u = blockIdx.x; u < 2048; u += nb) {
    const float4* w4 = (const float4*)(conv1_w + (size_t)u * CW3);
    const float4* m4 = (const float4*)(ws + OFF_MIX);
    float acc = 0.f;
#pragma unroll
    for (int p = tid; p < 512; p += 256) {
      float4 f0 = w4[3 * p], f1 = w4[3 * p + 1], f2 = w4[3 * p + 2];
      float4 m = m4[p];
      acc += f0.y * m.x + f1.x * m.y + f1.w * m.z + f2.z * m.w;
    }
    acc = wredf(acc);
    if (!lane) shf[wv] = acc;
    __syncthreads();
    if (!tid) (ws + OFF_OV)[u] = sigm(shf[0] + shf[1] + shf[2] + shf[3]);
    __syncthreads();
  }
  grid.sync();

  // ---- S8: final elementwise (overwrites all of d_out) ----
  {
    const float* scal = ws + OFF_SCAL;
    float mA = scal[0], cA = scal[1], mB = scal[2], cB = scal[3];
    for (int u = blockIdx.x; u < 2048; u += nb) {
      size_t base = (size_t)u * L;
      const float4* pa = (const float4*)(input + base);
      const float4* pb = (const float4*)(insum + base);
      float4* po = (float4*)(out + base);
      float ovc = (ws + OFF_OV)[u];
#pragma unroll
      for (int i = tid; i < L / 4; i += 256) {
        float4 a = pa[i], b = pb[i], r;
        r.x = (simam1(a.x, mA, cA) * 0.6f + simam1(b.x, mB, cB) * 0.4f) * ovc;
        r.y = (simam1(a.y, mA, cA) * 0.6f + simam1(b.y, mB, cB) * 0.4f) * ovc;
        r.z = (simam1(a.z, mA, cA) * 0.6f + simam1(b.z, mB, cB) * 0.4f) * ovc;
        r.w = (simam1(a.w, mA, cA) * 0.6f + simam1(b.w, mB, cB) * 0.4f) * ovc;
        po[i] = r;
      }
    }
  }
}

// ===================== fallback: proven round-2 multi-kernel path =====================
__global__ void kA(const float* __restrict__ A, const float* __restrict__ B,
                   const float* __restrict__ fc_w, float* __restrict__ ws,
                   float* __restrict__ sc) {
  int bx = blockIdx.x;
  if (bx < 4096) {
    __shared__ float l1[4], l2[4];
    const float* src = (bx < 2048) ? A : B;
    int row = (bx < 2048) ? bx : bx - 2048;
    float* rs = ws + ((bx < 2048) ? OFF_RS_A : OFF_RS_B);
    float* rq = ws + ((bx < 2048) ? OFF_RQ_A : OFF_RQ_B);
    const float4* p = (const float4*)(src + (size_t)row * L);
    float s = 0.f, q = 0.f;
#pragma unroll
    for (int i = threadIdx.x; i < L / 4; i += 256) {
      float4 v = p[i];
      s += (v.x + v.y) + (v.z + v.w);
      q += (v.x * v.x + v.y * v.y) + (v.z * v.z + v.w * v.w);
    }
    s = wredf(s); q = wredf(q);
    int lane = threadIdx.x & 63, w = threadIdx.x >> 6;
    if (!lane) { l1[w] = s; l2[w] = q; }
    __syncthreads();
    if (!threadIdx.x) {
      rs[row] = l1[0] + l1[1] + l1[2] + l1[3];
      rq[row] = l2[0] + l2[1] + l2[2] + l2[3];
    }
  } else {
    int cb = bx - 4096;
    int col = (cb & 7) * 256 + threadIdx.x;
    int r0 = (cb >> 3) * 64;
    const float* p = fc_w + (size_t)r0 * C + col;
    float acc = 0.f;
#pragma unroll 8
    for (int k = 0; k < 64; ++k) acc += p[(size_t)k * C];
    (sc + SC_CWP)[(cb >> 3) * C + col] = acc;
  }
}

__global__ void kB(const float* __restrict__ fc_w, const float* __restrict__ fc_b,
                   float* __restrict__ ws, const float* __restrict__ sc) {
  int bx = blockIdx.x;
  if (bx < 2048) {
    __shared__ float l[4];
    const float4* w = (const float4*)(fc_w + (size_t)bx * C);
    const float4* rx = (const float4*)(ws + OFF_RS_A);
    float acc = 0.f;
#pragma unroll
    for (int i = threadIdx.x; i < C / 4; i += 256) {
      float4 a = w[i], r = rx[i];
      acc += a.x * r.x + a.y * r.y + a.z * r.z + a.w * r.w;
    }
    acc = wredf(acc);
    int lane = threadIdx.x & 63, wv = threadIdx.x >> 6;
    if (!lane) l[wv] = acc;
    __syncthreads();
    if (!threadIdx.x)
      (ws + OFF_S)[bx] = 0.5f * (l[0] + l[1] + l[2] + l[3]) + (float)L2 * fc_b[bx];
  } else if (bx < 2056) {
    int i = (bx - 2048) * 256 + threadIdx.x;
    float acc = 0.f;
#pragma unroll
    for (int br = 0; br < 32; ++br) acc += (sc + SC_CWP)[br * C + i];
    (ws + OFF_CW)[i] = acc;
  } else if (bx == 2056) {
    __shared__ double sd[5];
    int lane = threadIdx.x & 63, w = threadIdx.x >> 6;
    const float* arr = ws + (w == 0 ? OFF_RS_A : w == 1 ? OFF_RQ_A
                                                        : w == 2 ? OFF_RS_B : OFF_RQ_B);
    double acc = 0.0, accb = 0.0;
    for (int i = lane; i < 2048; i += 64) {
      acc += (double)arr[i];
      if (w == 0) accb += (double)fc_b[i];
    }
    acc = wredd(acc);
    if (w == 0) accb = wredd(accb);
    if (!lane) { sd[w] = acc; if (w == 0) sd[4] = accb; }
    __syncthreads();
    if (!threadIdx.x) {
      const double N = (double)C * (double)L, n = N - 1.0;
      double dA = sd[1] - sd[0] * sd[0] / N;
      double dB = sd[3] - sd[2] * sd[2] / N;
      float* s = ws + OFF_SCAL;
      s[0] = (float)(sd[0] / N);
      s[1] = (float)(1.0 / (4.0 * (dA / n + 1e-4)));
      s[2] = (float)(sd[2] / N);
      s[3] = (float)(1.0 / (4.0 * (dB / n + 1e-4)));
      s[4] = (float)sd[4];
    }
  } else {
    size_t base = (size_t)(bx - 2057) * 2048;
#pragma unroll
    for (int j = 0; j < 8; ++j) ws[OFF_G + base + threadIdx.x + j * 256] = 0.f;
  }
}

__global__ void k3_gh(const float* __restrict__ conv1_w, float* __restrict__ ws) {
  if (blockIdx.y == 64) {
    if (blockIdx.x < 16) {
      int idx = blockIdx.x * 256 + threadIdx.x;
      ws[OFF_V + idx] = 0.f;
    }
    return;
  }
  __shared__ float lcw[32], ls[32];
  int col = blockIdx.x * 256 + threadIdx.x;
  int i0 = blockIdx.y * 32;
  if (threadIdx.x < 32) {
    lcw[threadIdx.x] = (ws + OFF_CW)[i0 + threadIdx.x];
    ls[threadIdx.x] = (ws + OFF_S)[i0 + threadIdx.x];
  }
  __syncthreads();
  const float* base = conv1_w + (size_t)i0 * CW3 + col;
  float ag = 0.f, ah = 0.f;
#pragma unroll 8
  for (int k = 0; k < 32; ++k) {
    float wv = base[(size_t)k * CW3];
    ag += lcw[k] * wv;
    ah += ls[k] * wv;
  }
  atomicAdd(ws + OFF_G + col, ag);
  atomicAdd(ws + OFF_H + col, ah);
}

__global__ void k4_vpart(const float* __restrict__ insum, float* __restrict__ ws) {
  int k = blockIdx.x * 256 + threadIdx.x;
  int c0 = blockIdx.y * 8;
  const float* g = ws + OFF_G;
  const float* h = ws + OFF_H;
  float accv = 0.f, acco = 0.f;
#pragma unroll
  for (int c = c0; c < c0 + 8; ++c) {
    const float* row = insum + (size_t)c * L;
    float2 bm = *(const float2*)(row + 2 * k);
    float xc = (bm.x + bm.y) * 0.5f;
    float xl = 0.f, xr = 0.f;
    if (k > 0) {
      float2 am = *(const float2*)(row + 2 * k - 2);
      xl = (am.x + am.y) * 0.5f;
    }
    if (k < L2 - 1) {
      float2 dm = *(const float2*)(row + 2 * k + 2);
      xr = (dm.x + dm.y) * 0.5f;
    }
    accv += g[c * 3] * xl + g[c * 3 + 1] * xc + g[c * 3 + 2] * xr;
    acco += h[c * 3] * xl + h[c * 3 + 1] * xc + h[c * 3 + 2] * xr;
  }
  atomicAdd(ws + OFF_V + k, accv);
  atomicAdd(ws + OFF_O2 + k, acco);
}

__global__ void k5_U(const float* __restrict__ input, float* __restrict__ ws) {
  __shared__ float l0[4], l1[4], l2s[4];
  int c = blockIdx.x;
  const float* v = ws + OFF_V;
  float sb = (ws + OFF_SCAL)[4];
  float a0 = 0.f, a1 = 0.f, a2 = 0.f;
  for (int j = threadIdx.x; j < L2; j += 256) {
    float2 ab = *(const float2*)(input + (size_t)c * L + 2 * j);
    float xmv = (ab.x + ab.y) * 0.5f;
    float vp = (j + 1 < L2) ? v[j + 1] + sb : 0.f;
    float vc = v[j] + sb;
    float vm = j ? v[j - 1] + sb : 0.f;
    a0 += xmv * vp;
    a1 += xmv * vc;
    a2 += xmv * vm;
  }
  a0 = wredf(a0); a1 = wredf(a1); a2 = wredf(a2);
  int lane = threadIdx.x & 63, w = threadIdx.x >> 6;
  if (!lane) { l0[w] = a0; l1[w] = a1; l2s[w] = a2; }
  __syncthreads();
  if (!threadIdx.x) {
    (ws + OFF_U)[c * 3 + 0] = l0[0] + l0[1] + l0[2] + l0[3];
    (ws + OFF_U)[c * 3 + 1] = l1[0] + l1[1] + l1[2] + l1[3];
    (ws + OFF_U)[c * 3 + 2] = l2s[0] + l2s[1] + l2s[2] + l2s[3];
  }
}

__global__ void k6_out1(const float* __restrict__ conv1_w, const float* __restrict__ mix_w,
                        float* __restrict__ ws) {
  __shared__ float l[4];
  int a = blockIdx.x;
  const float4* w4 = (const float4*)(conv1_w + (size_t)a * CW3);
  const float4* u4 = (const float4*)(ws + OFF_U);
  float acc = 0.f;
#pragma unroll
  for (int m = threadIdx.x; m < CW3 / 4; m += 256) {
    float4 wv = w4[m], uv = u4[m];
    acc += wv.x * uv.x + wv.y * uv.y + wv.z * uv.z + wv.w * uv.w;
  }
  acc = wredf(acc);
  int lane = threadIdx.x & 63, w = threadIdx.x >> 6;
  if (!lane) l[w] = acc;
  __syncthreads();
  if (!threadIdx.x) {
    float mfv = sigm(mix_w[0]);
    float o1 = sigm(l[0] + l[1] + l[2] + l[3]);
    float o2 = sigm((ws + OFF_O2)[a]);
    (ws + OFF_MIX)[a] = o1 * mfv + o2 * (1.f - mfv);
  }
}

__global__ void k7_ov(const float* __restrict__ conv1_w, float* __restrict__ ws) {
  __shared__ float l[4];
  int a = blockIdx.x;
  const float4* w4 = (const float4*)(conv1_w + (size_t)a * CW3);
  const float4* m4 = (const float4*)(ws + OFF_MIX);
  float acc = 0.f;
#pragma unroll
  for (int p = threadIdx.x; p < 512; p += 256) {
    float4 f0 = w4[3 * p], f1 = w4[3 * p + 1], f2 = w4[3 * p + 2];
    float4 m = m4[p];
    acc += f0.y * m.x + f1.x * m.y + f1.w * m.z + f2.z * m.w;
  }
  acc = wredf(acc);
  int lane = threadIdx.x & 63, w = threadIdx.x >> 6;
  if (!lane) l[w] = acc;
  __syncthreads();
  if (!threadIdx.x) (ws + OFF_OV)[a] = sigm(l[0] + l[1] + l[2] + l[3]);
}

__global__ void k8_final(const float* __restrict__ input, const float* __restrict__ insum,
                         float* __restrict__ out, const float* __restrict__ ws) {
  int c = blockIdx.x;
  size_t base = (size_t)c * L + (size_t)blockIdx.y * (L / 2);
  const float4* pa = (const float4*)(input + base);
  const float4* pb = (const float4*)(insum + base);
  float4* po = (float4*)(out + base);
  const float* scal = ws + OFF_SCAL;
  float mA = scal[0], cA = scal[1], mB = scal[2], cB = scal[3];
  float ovc = (ws + OFF_OV)[c];
#pragma unroll
  for (int i = threadIdx.x; i < L / 8; i += 256) {
    float4 a = pa[i], b = pb[i], r;
    r.x = (simam1(a.x, mA, cA) * 0.6f + simam1(b.x, mB, cB) * 0.4f) * ovc;
    r.y = (simam1(a.y, mA, cA) * 0.6f + simam1(b.y, mB, cB) * 0.4f) * ovc;
    r.z = (simam1(a.z, mA, cA) * 0.6f + simam1(b.z, mB, cB) * 0.4f) * ovc;
    r.w = (simam1(a.w, mA, cA) * 0.6f + simam1(b.w, mB, cB) * 0.4f) * ovc;
    po[i] = r;
  }
}

extern "C" void kernel_launch(void* const* d_in, const int* in_sizes, int n_in,
                              void* d_out, int out_size, void* d_ws, size_t ws_size,
                              hipStream_t stream) {
  const float* input   = (const float*)d_in[0];
  const float* insum   = (const float*)d_in[1];
  const float* conv1_w = (const float*)d_in[2];
  const float* fc_w    = (const float*)d_in[3];
  const float* fc_b    = (const float*)d_in[4];
  const float* mix_w   = (const float*)d_in[5];
  float* out = (float*)d_out;
  float* ws  = (float*)d_ws;
  float* sc  = out;

  void* args[] = {(void*)&input, (void*)&insum, (void*)&conv1_w, (void*)&fc_w,
                  (void*)&fc_b, (void*)&mix_w, (void*)&out, (void*)&ws};
  hipError_t err = hipLaunchCooperativeKernel((const void*)mega, dim3(1024), dim3(256),
                                              args, 0, stream);
  if (err != hipSuccess) {
    // fallback: proven multi-kernel path
    dim3 b(256);
    kA<<<4352, b, 0, stream>>>(input, insum, fc_w, ws, sc);
    kB<<<2063, b, 0, stream>>>(fc_w, fc_b, ws, sc);
    k3_gh<<<dim3(24, 65), b, 0, stream>>>(conv1_w, ws);
    k4_vpart<<<dim3(8, 256), b, 0, stream>>>(insum, ws);
    k5_U<<<C, b, 0, stream>>>(input, ws);
    k6_out1<<<C, b, 0, stream>>>(conv1_w, mix_w, ws);
    k7_ov<<<C, b, 0, stream>>>(conv1_w, ws);
    k8_final<<<dim3(C, 2), b, 0, stream>>>(input, insum, out, ws);
  }
}